// Round 1
// baseline (382.281 us; speedup 1.0000x reference)
//
#include <hip/hip_runtime.h>
#include <hip/hip_bf16.h>
#include <math.h>

#define BATCH 4
#define P 1024
#define D 1024
#define NREF 256
#define M_EXTRA 4096
#define TOPK 4

// ---------------- workspace layout (floats) ----------------
// [0..15]            acc[3] (+pad)
// [16 .. 16+16383]   inv_norm[B*4096]
// [16400 .. +4194303] scores[B*256*4096]
// then topk int[B*256*4]
#define WS_ACC 0
#define WS_INVNORM 16
#define WS_SCORES (16 + BATCH * M_EXTRA)

// ---------------- K1: inverse norms of extra_t rows ----------------
__global__ __launch_bounds__(256) void norm_kernel(const float* __restrict__ teacher,
                                                   float* __restrict__ inv_norm) {
    int row = blockIdx.x;            // b*4096 + m
    int b = row >> 12;
    int m = row & 4095;
    int frame = 1 + 2 * (m >> 10);
    int p = m & 1023;
    const float* src = teacher + (((size_t)b * 8 + frame) * 1024 + p) * 1024;
    float4 v = ((const float4*)src)[threadIdx.x];
    float s = v.x * v.x + v.y * v.y + v.z * v.z + v.w * v.w;
    for (int o = 32; o > 0; o >>= 1) s += __shfl_xor(s, o);
    __shared__ float red[4];
    if ((threadIdx.x & 63) == 0) red[threadIdx.x >> 6] = s;
    __syncthreads();
    if (threadIdx.x == 0) {
        float tot = red[0] + red[1] + red[2] + red[3];
        inv_norm[row] = 1.0f / fmaxf(sqrtf(tot), 1e-12f);
    }
}

// ---------------- K2: fp32 tiled GEMM: scores = (ref_t . extra_t^T) * inv_norm_extra ----------------
__global__ __launch_bounds__(256) void gemm_kernel(const float* __restrict__ teacher,
                                                   const int* __restrict__ ref_perm,
                                                   const float* __restrict__ inv_norm,
                                                   float* __restrict__ scores) {
    int mt = blockIdx.x;   // 0..63
    int nt = blockIdx.y;   // 0..3
    int b  = blockIdx.z;   // 0..3
    int t = threadIdx.x;

    __shared__ float As[16][64];   // [k][n]
    __shared__ float Bs[16][64];   // [k][m]
    __shared__ int aperm[64];
    if (t < 64) aperm[t] = ref_perm[nt * 64 + t];
    __syncthreads();

    int lr = t >> 2;            // 0..63 tile row
    int lc = (t & 3) * 4;       // 0,4,8,12 k offset
    int tx = t & 15, ty = t >> 4;

    const size_t base_b = (size_t)b * 8 * 1024 * 1024;
    const float* Arow = teacher + base_b + (size_t)aperm[lr] * 1024;
    int mrow = mt * 64 + lr;
    const float* Brow = teacher + base_b +
        ((size_t)(1 + 2 * (mrow >> 10)) * 1024 + (mrow & 1023)) * 1024;

    float acc[4][4] = {};

    for (int k0 = 0; k0 < 1024; k0 += 16) {
        float4 a4 = *(const float4*)(Arow + k0 + lc);
        float4 b4 = *(const float4*)(Brow + k0 + lc);
        __syncthreads();
        As[lc + 0][lr] = a4.x; As[lc + 1][lr] = a4.y;
        As[lc + 2][lr] = a4.z; As[lc + 3][lr] = a4.w;
        Bs[lc + 0][lr] = b4.x; Bs[lc + 1][lr] = b4.y;
        Bs[lc + 2][lr] = b4.z; Bs[lc + 3][lr] = b4.w;
        __syncthreads();
#pragma unroll
        for (int k = 0; k < 16; k++) {
            float4 av = *(const float4*)&As[k][ty * 4];
            float4 bv = *(const float4*)&Bs[k][tx * 4];
            float a[4] = {av.x, av.y, av.z, av.w};
            float bb[4] = {bv.x, bv.y, bv.z, bv.w};
#pragma unroll
            for (int i = 0; i < 4; i++)
#pragma unroll
                for (int j = 0; j < 4; j++)
                    acc[i][j] = fmaf(a[i], bb[j], acc[i][j]);
        }
    }

#pragma unroll
    for (int i = 0; i < 4; i++) {
        int n = nt * 64 + ty * 4 + i;
#pragma unroll
        for (int j = 0; j < 4; j++) {
            int m = mt * 64 + tx * 4 + j;
            scores[((size_t)(b * 256 + n)) * 4096 + m] = acc[i][j] * inv_norm[b * 4096 + m];
        }
    }
}

// ---------------- K3: top-4 per (b,n) row ----------------
__global__ __launch_bounds__(64) void topk_kernel(const float* __restrict__ scores,
                                                  int* __restrict__ topk) {
    int row = blockIdx.x;       // b*256 + n
    int lane = threadIdx.x;     // 0..63
    const float* s = scores + (size_t)row * 4096;
    float v[4] = {-1e38f, -1e38f, -1e38f, -1e38f};
    int ix[4] = {-1, -1, -1, -1};
    for (int m = lane; m < 4096; m += 64) {
        float x = s[m];
        if (x > v[3]) {
            v[3] = x; ix[3] = m;
#pragma unroll
            for (int i = 3; i > 0; i--) {
                if (v[i] > v[i - 1]) {
                    float tv = v[i]; v[i] = v[i - 1]; v[i - 1] = tv;
                    int ti = ix[i]; ix[i] = ix[i - 1]; ix[i - 1] = ti;
                }
            }
        }
    }
    for (int r = 0; r < 4; r++) {
        float bv = v[0]; int bi = ix[0];
        for (int o = 32; o > 0; o >>= 1) {
            float ov = __shfl_xor(bv, o);
            int oi = __shfl_xor(bi, o);
            if (ov > bv || (ov == bv && oi < bi)) { bv = ov; bi = oi; }
        }
        if (lane == 0) topk[row * 4 + r] = bi;
        if (bi == ix[0]) {
            v[0] = v[1]; ix[0] = ix[1];
            v[1] = v[2]; ix[1] = ix[2];
            v[2] = v[3]; ix[2] = ix[3];
            v[3] = -1e38f; ix[3] = -1;
        }
    }
}

// ---------------- K4: fused KL branches ----------------
__global__ __launch_bounds__(256) void kl_kernel(const float* __restrict__ teacher,
                                                 const float* __restrict__ student,
                                                 const int* __restrict__ ref_perm,
                                                 const int* __restrict__ shared_perm,
                                                 const int* __restrict__ topk,
                                                 float* __restrict__ acc) {
    int row = blockIdx.x;        // b*256 + n
    int b = row >> 8;
    int n = row & 255;
    int t = threadIdx.x;
    int lane = t & 63, wave = t >> 6;

    __shared__ float rt[1024], rs[1024], st[1024], ss[1024];
    __shared__ float sh[4][1024];
    __shared__ float res3[3];
    if (t < 3) res3[t] = 0.f;

    const float* Tb = teacher + (size_t)b * 8 * 1024 * 1024;
    const float* Sb = student + (size_t)b * 4 * 1024 * 1024;

    int rp = ref_perm[n];
    ((float4*)rt)[t] = ((const float4*)(Tb + (size_t)rp * 1024))[t];
    ((float4*)rs)[t] = ((const float4*)(Sb + (size_t)rp * 1024))[t];
#pragma unroll
    for (int k = 0; k < 4; k++) {
        int idx = topk[row * 4 + k];
        int frame = 1 + 2 * (idx >> 10), p = idx & 1023;
        ((float4*)sh[k])[t] = ((const float4*)(Tb + ((size_t)frame * 1024 + p) * 1024))[t];
    }
    int sp = shared_perm[n];

    for (int ti = 0; ti < 3; ti++) {
        int t_idx = 2 * ti + 2;
        int s_idx = ti + 1;
        __syncthreads();   // previous iteration's reads done; also covers initial loads/res3
        ((float4*)st)[t] = ((const float4*)(Tb + ((size_t)t_idx * 1024 + sp) * 1024))[t];
        ((float4*)ss)[t] = ((const float4*)(Sb + ((size_t)s_idx * 1024 + sp) * 1024))[t];
        __syncthreads();

        for (int r = wave; r < 9; r += 4) {
            const float *At, *Bt, *Asx, *Bsx;
            int branch;
            if (r == 0)      { At = rt; Bt = st;        Asx = rs; Bsx = ss;        branch = 0; }
            else if (r < 5)  { At = rt; Bt = sh[r - 1]; Asx = rs; Bsx = sh[r - 1]; branch = 1; }
            else             { At = st; Bt = sh[r - 5]; Asx = ss; Bsx = sh[r - 5]; branch = 2; }

            float dt[16], ds[16];
            float mt = -1e38f, ms = -1e38f;
#pragma unroll
            for (int j = 0; j < 16; j++) {
                int d = lane + 64 * j;
                dt[j] = At[d] - Bt[d];
                ds[j] = Asx[d] - Bsx[d];
                mt = fmaxf(mt, dt[j]);
                ms = fmaxf(ms, ds[j]);
            }
            for (int o = 32; o > 0; o >>= 1) {
                mt = fmaxf(mt, __shfl_xor(mt, o));
                ms = fmaxf(ms, __shfl_xor(ms, o));
            }
            float Zt = 0.f, Zs = 0.f, Tn = 0.f;
#pragma unroll
            for (int j = 0; j < 16; j++) {
                float et = __expf(dt[j] - mt);
                Zt += et;
                Zs += __expf(ds[j] - ms);
                Tn += et * (dt[j] - ds[j]);
            }
            for (int o = 32; o > 0; o >>= 1) {
                Zt += __shfl_xor(Zt, o);
                Zs += __shfl_xor(Zs, o);
                Tn += __shfl_xor(Tn, o);
            }
            if (lane == 0) {
                float kl = Tn / Zt - mt - __logf(Zt) + ms + __logf(Zs);
                float ax = fabsf(kl);
                float h = ax < 0.5f ? ax * ax : ax - 0.25f;
                atomicAdd(&res3[branch], h);
            }
        }
    }
    __syncthreads();
    if (t < 3) atomicAdd(&acc[t], res3[t]);
}

// ---------------- K5: finalize ----------------
__global__ void finalize_kernel(const float* __restrict__ acc, float* __restrict__ out) {
    out[0] = acc[0] / 3072.f + acc[1] / 12288.f + acc[2] / 12288.f;
}

extern "C" void kernel_launch(void* const* d_in, const int* in_sizes, int n_in,
                              void* d_out, int out_size, void* d_ws, size_t ws_size,
                              hipStream_t stream) {
    const float* teacher = (const float*)d_in[0];
    const float* student = (const float*)d_in[1];
    const int* ref_perm = (const int*)d_in[2];
    const int* shared_perm = (const int*)d_in[3];
    float* out = (float*)d_out;

    float* ws = (float*)d_ws;
    float* acc = ws + WS_ACC;
    float* inv_norm = ws + WS_INVNORM;
    float* scores = ws + WS_SCORES;
    int* topk = (int*)(scores + (size_t)BATCH * NREF * M_EXTRA);

    hipMemsetAsync(acc, 0, 16 * sizeof(float), stream);

    norm_kernel<<<BATCH * M_EXTRA, 256, 0, stream>>>(teacher, inv_norm);
    gemm_kernel<<<dim3(64, 4, 4), 256, 0, stream>>>(teacher, ref_perm, inv_norm, scores);
    topk_kernel<<<BATCH * NREF, 64, 0, stream>>>(scores, topk);
    kl_kernel<<<BATCH * NREF, 256, 0, stream>>>(teacher, student, ref_perm, shared_perm, topk, acc);
    finalize_kernel<<<1, 1, 0, stream>>>(acc, out);
}

// Round 2
// 302.152 us; speedup vs baseline: 1.2652x; 1.2652x over previous
//
#include <hip/hip_runtime.h>
#include <hip/hip_bf16.h>
#include <math.h>

#define BATCH 4

typedef __bf16 bf16x8 __attribute__((ext_vector_type(8)));
typedef float f32x4 __attribute__((ext_vector_type(4)));

#define LDSTRIDE 40  // bf16 units per LDS row (80 B): 5r+q mod 8 -> conflict-free b128 reads

// ---------------- K1: convert teacher rows to bf16 (extra rows pre-normalized) ----------------
__global__ __launch_bounds__(256) void convert_kernel(const float* __restrict__ teacher,
                                                      const int* __restrict__ ref_perm,
                                                      __bf16* __restrict__ Abf,
                                                      __bf16* __restrict__ Bbf,
                                                      float* __restrict__ invnorm) {
    int blk = blockIdx.x;            // b*4352 + r
    int b = blk / 4352;
    int r = blk - b * 4352;
    int t = threadIdx.x;
    const float* src;
    __bf16* dst;
    bool isB = (r >= 256);
    if (!isB) {
        src = teacher + (((size_t)b * 8 + 0) * 1024 + ref_perm[r]) * 1024;
        dst = Abf + ((size_t)b * 256 + r) * 1024;
    } else {
        int m = r - 256;
        int frame = 1 + 2 * (m >> 10), p = m & 1023;
        src = teacher + (((size_t)b * 8 + frame) * 1024 + p) * 1024;
        dst = Bbf + ((size_t)b * 4096 + m) * 1024;
    }
    float4 v = ((const float4*)src)[t];
    float scale = 1.0f;
    __shared__ float red[4];
    if (isB) {
        float s = v.x * v.x + v.y * v.y + v.z * v.z + v.w * v.w;
        for (int o = 32; o > 0; o >>= 1) s += __shfl_xor(s, o);
        if ((t & 63) == 0) red[t >> 6] = s;
        __syncthreads();
        float tot = red[0] + red[1] + red[2] + red[3];
        scale = 1.0f / fmaxf(sqrtf(tot), 1e-12f);
        if (t == 0) invnorm[b * 4096 + (r - 256)] = scale;
    }
    __bf16 o4[4] = {(__bf16)(v.x * scale), (__bf16)(v.y * scale),
                    (__bf16)(v.z * scale), (__bf16)(v.w * scale)};
    ((uint2*)dst)[t] = *(uint2*)o4;
}

// ---------------- K2: bf16 MFMA GEMM: scoresb[b][n][m] = A[n,:] . B[m,:] ----------------
__global__ __launch_bounds__(256) void mfma_gemm_kernel(const __bf16* __restrict__ Abf,
                                                        const __bf16* __restrict__ Bbf,
                                                        __bf16* __restrict__ scoresb) {
    int mt = blockIdx.x;    // 0..31
    int nt = blockIdx.y;    // 0..1
    int b  = blockIdx.z;    // 0..3
    int t = threadIdx.x;
    int lane = t & 63, wave = t >> 6;
    int wn0 = (wave & 1) * 64;
    int wm0 = (wave >> 1) * 64;
    int l15 = lane & 15, l4 = lane >> 4;

    __shared__ __bf16 As[128 * LDSTRIDE];
    __shared__ __bf16 Bs[128 * LDSTRIDE];

    const __bf16* Ab = Abf + ((size_t)b * 256 + nt * 128) * 1024;
    const __bf16* Bb = Bbf + ((size_t)b * 4096 + mt * 128) * 1024;

    int e0 = t, e1 = t + 256;
    int row0 = e0 >> 2, kc0 = e0 & 3;
    int row1 = e1 >> 2, kc1 = e1 & 3;

    f32x4 acc[4][4] = {};

    for (int k0 = 0; k0 < 1024; k0 += 32) {
        uint4 a0 = *(const uint4*)(Ab + (size_t)row0 * 1024 + k0 + kc0 * 8);
        uint4 a1 = *(const uint4*)(Ab + (size_t)row1 * 1024 + k0 + kc1 * 8);
        uint4 b0 = *(const uint4*)(Bb + (size_t)row0 * 1024 + k0 + kc0 * 8);
        uint4 b1 = *(const uint4*)(Bb + (size_t)row1 * 1024 + k0 + kc1 * 8);
        __syncthreads();   // prev iter's frag reads complete
        *(uint4*)(As + row0 * LDSTRIDE + kc0 * 8) = a0;
        *(uint4*)(As + row1 * LDSTRIDE + kc1 * 8) = a1;
        *(uint4*)(Bs + row0 * LDSTRIDE + kc0 * 8) = b0;
        *(uint4*)(Bs + row1 * LDSTRIDE + kc1 * 8) = b1;
        __syncthreads();
        bf16x8 af[4], bfr[4];
#pragma unroll
        for (int i = 0; i < 4; i++) {
            af[i]  = *(const bf16x8*)(As + (wn0 + i * 16 + l15) * LDSTRIDE + l4 * 8);
            bfr[i] = *(const bf16x8*)(Bs + (wm0 + i * 16 + l15) * LDSTRIDE + l4 * 8);
        }
#pragma unroll
        for (int i = 0; i < 4; i++)
#pragma unroll
            for (int j = 0; j < 4; j++)
                acc[i][j] = __builtin_amdgcn_mfma_f32_16x16x32_bf16(af[i], bfr[j], acc[i][j], 0, 0, 0);
    }

    __bf16* outp = scoresb + ((size_t)b * 256 + nt * 128) * 4096 + (size_t)mt * 128;
#pragma unroll
    for (int i = 0; i < 4; i++)
#pragma unroll
        for (int j = 0; j < 4; j++)
#pragma unroll
            for (int r = 0; r < 4; r++) {
                int n = wn0 + i * 16 + l4 * 4 + r;
                int m = wm0 + j * 16 + l15;
                outp[(size_t)n * 4096 + m] = (__bf16)acc[i][j][r];
            }
}

// ---------------- K3: top-8 (approx) -> exact fp32 rescore -> top-4 ----------------
__global__ __launch_bounds__(256) void topk_rescore_kernel(const __bf16* __restrict__ scoresb,
                                                           const float* __restrict__ teacher,
                                                           const int* __restrict__ ref_perm,
                                                           const float* __restrict__ invnorm,
                                                           int* __restrict__ topk) {
    int row = blockIdx.x;  // b*256+n
    int b = row >> 8, n = row & 255;
    int t = threadIdx.x;
    int lane = t & 63, wave = t >> 6;

    __shared__ float refr[1024];
    __shared__ float cval[32];
    __shared__ int cidx[32];
    __shared__ float exact_v[8];
    __shared__ int exact_i[8];

    const float* Tb = teacher + (size_t)b * 8 * 1024 * 1024;
    int rp = ref_perm[n];
    ((float4*)refr)[t] = ((const float4*)(Tb + (size_t)rp * 1024))[t];

    const __bf16* srow = scoresb + (size_t)row * 4096;
    float v[8]; int ix[8];
#pragma unroll
    for (int i = 0; i < 8; i++) { v[i] = -1e38f; ix[i] = -1; }
    for (int jj = 0; jj < 16; jj++) {
        int m = t + 256 * jj;
        float x = (float)srow[m];
        if (x > v[7]) {
            v[7] = x; ix[7] = m;
#pragma unroll
            for (int i = 7; i > 0; i--)
                if (v[i] > v[i - 1] || (v[i] == v[i - 1] && ix[i] > ix[i - 1])) {
                    float tv = v[i]; v[i] = v[i - 1]; v[i - 1] = tv;
                    int ti = ix[i]; ix[i] = ix[i - 1]; ix[i - 1] = ti;
                }
        }
    }
    // wave-level top-8 (deterministic (val, idx) order so all lanes agree)
    int h = 0;
    for (int r = 0; r < 8; r++) {
        float bv = (h < 8) ? v[h] : -1e38f;
        int bi = (h < 8) ? ix[h] : -1;
        int bl = lane;
        for (int o = 32; o > 0; o >>= 1) {
            float ov = __shfl_xor(bv, o); int oi = __shfl_xor(bi, o); int ol = __shfl_xor(bl, o);
            if (ov > bv || (ov == bv && oi > bi)) { bv = ov; bi = oi; bl = ol; }
        }
        if (lane == 0) { cval[wave * 8 + r] = bv; cidx[wave * 8 + r] = bi; }
        if (bl == lane) h++;
    }
    __syncthreads();
    // block merge: wave 0 reduces 32 candidates -> top-8
    if (wave == 0) {
        float mv = (lane < 32) ? cval[lane] : -1e38f;
        int mi = (lane < 32) ? cidx[lane] : -1;
        for (int r = 0; r < 8; r++) {
            float bv = mv; int bi = mi; int bl = lane;
            for (int o = 32; o > 0; o >>= 1) {
                float ov = __shfl_xor(bv, o); int oi = __shfl_xor(bi, o); int ol = __shfl_xor(bl, o);
                if (ov > bv || (ov == bv && oi > bi)) { bv = ov; bi = oi; bl = ol; }
            }
            if (lane == 0) exact_i[r] = bi;
            if (bl == lane) mv = -1e38f;
        }
    }
    __syncthreads();
    // exact fp32 rescore of the 8 candidates
    for (int c = wave; c < 8; c += 4) {
        int m = exact_i[c];
        int frame = 1 + 2 * (m >> 10), p = m & 1023;
        const float* ext = Tb + ((size_t)frame * 1024 + p) * 1024;
        float s = 0.f;
        for (int jj = 0; jj < 16; jj++) {
            int d = lane + 64 * jj;
            s = fmaf(refr[d], ext[d], s);
        }
        for (int o = 32; o > 0; o >>= 1) s += __shfl_xor(s, o);
        if (lane == 0) exact_v[c] = s * invnorm[b * 4096 + m];
    }
    __syncthreads();
    if (t == 0) {
        unsigned used = 0;
        for (int r = 0; r < 4; r++) {
            float bv = -1e38f; int bc = 0;
            for (int c = 0; c < 8; c++)
                if (!(used & (1u << c)) && exact_v[c] > bv) { bv = exact_v[c]; bc = c; }
            used |= 1u << bc;
            topk[row * 4 + r] = exact_i[bc];
        }
    }
}

// ---------------- K4: fused KL branches ----------------
__global__ __launch_bounds__(256) void kl_kernel(const float* __restrict__ teacher,
                                                 const float* __restrict__ student,
                                                 const int* __restrict__ ref_perm,
                                                 const int* __restrict__ shared_perm,
                                                 const int* __restrict__ topk,
                                                 float* __restrict__ acc) {
    int row = blockIdx.x;        // b*256 + n
    int b = row >> 8;
    int n = row & 255;
    int t = threadIdx.x;
    int lane = t & 63, wave = t >> 6;

    __shared__ float rt[1024], rs[1024], st[1024], ss[1024];
    __shared__ float sh[4][1024];
    __shared__ float res3[3];
    if (t < 3) res3[t] = 0.f;

    const float* Tb = teacher + (size_t)b * 8 * 1024 * 1024;
    const float* Sb = student + (size_t)b * 4 * 1024 * 1024;

    int rp = ref_perm[n];
    ((float4*)rt)[t] = ((const float4*)(Tb + (size_t)rp * 1024))[t];
    ((float4*)rs)[t] = ((const float4*)(Sb + (size_t)rp * 1024))[t];
#pragma unroll
    for (int k = 0; k < 4; k++) {
        int idx = topk[row * 4 + k];
        int frame = 1 + 2 * (idx >> 10), p = idx & 1023;
        ((float4*)sh[k])[t] = ((const float4*)(Tb + ((size_t)frame * 1024 + p) * 1024))[t];
    }
    int sp = shared_perm[n];

    for (int ti = 0; ti < 3; ti++) {
        int t_idx = 2 * ti + 2;
        int s_idx = ti + 1;
        __syncthreads();
        ((float4*)st)[t] = ((const float4*)(Tb + ((size_t)t_idx * 1024 + sp) * 1024))[t];
        ((float4*)ss)[t] = ((const float4*)(Sb + ((size_t)s_idx * 1024 + sp) * 1024))[t];
        __syncthreads();

        for (int r = wave; r < 9; r += 4) {
            const float *At, *Bt, *Asx, *Bsx;
            int branch;
            if (r == 0)      { At = rt; Bt = st;        Asx = rs; Bsx = ss;        branch = 0; }
            else if (r < 5)  { At = rt; Bt = sh[r - 1]; Asx = rs; Bsx = sh[r - 1]; branch = 1; }
            else             { At = st; Bt = sh[r - 5]; Asx = ss; Bsx = sh[r - 5]; branch = 2; }

            float dt[16], ds[16];
            float mt = -1e38f, ms = -1e38f;
#pragma unroll
            for (int j = 0; j < 16; j++) {
                int d = lane + 64 * j;
                dt[j] = At[d] - Bt[d];
                ds[j] = Asx[d] - Bsx[d];
                mt = fmaxf(mt, dt[j]);
                ms = fmaxf(ms, ds[j]);
            }
            for (int o = 32; o > 0; o >>= 1) {
                mt = fmaxf(mt, __shfl_xor(mt, o));
                ms = fmaxf(ms, __shfl_xor(ms, o));
            }
            float Zt = 0.f, Zs = 0.f, Tn = 0.f;
#pragma unroll
            for (int j = 0; j < 16; j++) {
                float et = __expf(dt[j] - mt);
                Zt += et;
                Zs += __expf(ds[j] - ms);
                Tn += et * (dt[j] - ds[j]);
            }
            for (int o = 32; o > 0; o >>= 1) {
                Zt += __shfl_xor(Zt, o);
                Zs += __shfl_xor(Zs, o);
                Tn += __shfl_xor(Tn, o);
            }
            if (lane == 0) {
                float kl = Tn / Zt - mt - __logf(Zt) + ms + __logf(Zs);
                float ax = fabsf(kl);
                float h = ax < 0.5f ? ax * ax : ax - 0.25f;
                atomicAdd(&res3[branch], h);
            }
        }
    }
    __syncthreads();
    if (t < 3) atomicAdd(&acc[t], res3[t]);
}

// ---------------- K5: finalize ----------------
__global__ void finalize_kernel(const float* __restrict__ acc, float* __restrict__ out) {
    out[0] = acc[0] / 3072.f + acc[1] / 12288.f + acc[2] / 12288.f;
}

extern "C" void kernel_launch(void* const* d_in, const int* in_sizes, int n_in,
                              void* d_out, int out_size, void* d_ws, size_t ws_size,
                              hipStream_t stream) {
    const float* teacher = (const float*)d_in[0];
    const float* student = (const float*)d_in[1];
    const int* ref_perm = (const int*)d_in[2];
    const int* shared_perm = (const int*)d_in[3];
    float* out = (float*)d_out;

    char* ws = (char*)d_ws;
    float* acc     = (float*)ws;                         // 64 B
    float* invnorm = (float*)(ws + 64);                  // 16384 floats
    int*   topk    = (int*)(ws + 64 + 65536);            // 4096 ints
    __bf16* Abf    = (__bf16*)(ws + 64 + 65536 + 16384); // 4*256*1024
    __bf16* Bbf    = Abf + (size_t)4 * 256 * 1024;       // 4*4096*1024
    __bf16* scoresb = Bbf + (size_t)4 * 4096 * 1024;     // 4*256*4096

    hipMemsetAsync(acc, 0, 64, stream);

    convert_kernel<<<BATCH * 4352, 256, 0, stream>>>(teacher, ref_perm, Abf, Bbf, invnorm);
    mfma_gemm_kernel<<<dim3(32, 2, 4), 256, 0, stream>>>(Abf, Bbf, scoresb);
    topk_rescore_kernel<<<1024, 256, 0, stream>>>(scoresb, teacher, ref_perm, invnorm, topk);
    kl_kernel<<<1024, 256, 0, stream>>>(teacher, student, ref_perm, shared_perm, topk, acc);
    finalize_kernel<<<1, 1, 0, stream>>>(acc, out);
}

// Round 3
// 282.384 us; speedup vs baseline: 1.3538x; 1.0700x over previous
//
#include <hip/hip_runtime.h>
#include <hip/hip_bf16.h>
#include <math.h>

#define BATCH 4

typedef __bf16 bf16x8 __attribute__((ext_vector_type(8)));
typedef float f32x4 __attribute__((ext_vector_type(4)));

#define LDSTRIDE 40  // bf16 units per LDS row (80 B): conflict-free b128 reads

// ---------------- K1: convert teacher rows to bf16 (extra rows pre-normalized) ----------------
__global__ __launch_bounds__(256) void convert_kernel(const float* __restrict__ teacher,
                                                      const int* __restrict__ ref_perm,
                                                      __bf16* __restrict__ Abf,
                                                      __bf16* __restrict__ Bbf,
                                                      float* __restrict__ invnorm) {
    int blk = blockIdx.x;            // b*4352 + r
    int b = blk / 4352;
    int r = blk - b * 4352;
    int t = threadIdx.x;
    const float* src;
    __bf16* dst;
    bool isB = (r >= 256);
    if (!isB) {
        src = teacher + (((size_t)b * 8 + 0) * 1024 + ref_perm[r]) * 1024;
        dst = Abf + ((size_t)b * 256 + r) * 1024;
    } else {
        int m = r - 256;
        int frame = 1 + 2 * (m >> 10), p = m & 1023;
        src = teacher + (((size_t)b * 8 + frame) * 1024 + p) * 1024;
        dst = Bbf + ((size_t)b * 4096 + m) * 1024;
    }
    float4 v = ((const float4*)src)[t];
    float scale = 1.0f;
    __shared__ float red[4];
    if (isB) {
        float s = v.x * v.x + v.y * v.y + v.z * v.z + v.w * v.w;
        for (int o = 32; o > 0; o >>= 1) s += __shfl_xor(s, o);
        if ((t & 63) == 0) red[t >> 6] = s;
        __syncthreads();
        float tot = red[0] + red[1] + red[2] + red[3];
        scale = 1.0f / fmaxf(sqrtf(tot), 1e-12f);
        if (t == 0) invnorm[b * 4096 + (r - 256)] = scale;
    }
    __bf16 o4[4] = {(__bf16)(v.x * scale), (__bf16)(v.y * scale),
                    (__bf16)(v.z * scale), (__bf16)(v.w * scale)};
    ((uint2*)dst)[t] = *(uint2*)o4;
}

// ---------------- K2: bf16 MFMA GEMM: scoresb[b][n][m] = A[n,:] . B[m,:] ----------------
__global__ __launch_bounds__(256) void mfma_gemm_kernel(const __bf16* __restrict__ Abf,
                                                        const __bf16* __restrict__ Bbf,
                                                        __bf16* __restrict__ scoresb) {
    int mt = blockIdx.x;    // 0..31
    int nt = blockIdx.y;    // 0..1
    int b  = blockIdx.z;    // 0..3
    int t = threadIdx.x;
    int lane = t & 63, wave = t >> 6;
    int wn0 = (wave & 1) * 64;
    int wm0 = (wave >> 1) * 64;
    int l15 = lane & 15, l4 = lane >> 4;

    __shared__ __bf16 As[128 * LDSTRIDE];
    __shared__ __bf16 Bs[128 * LDSTRIDE];

    const __bf16* Ab = Abf + ((size_t)b * 256 + nt * 128) * 1024;
    const __bf16* Bb = Bbf + ((size_t)b * 4096 + mt * 128) * 1024;

    int e0 = t, e1 = t + 256;
    int row0 = e0 >> 2, kc0 = e0 & 3;
    int row1 = e1 >> 2, kc1 = e1 & 3;

    f32x4 acc[4][4] = {};

    for (int k0 = 0; k0 < 1024; k0 += 32) {
        uint4 a0 = *(const uint4*)(Ab + (size_t)row0 * 1024 + k0 + kc0 * 8);
        uint4 a1 = *(const uint4*)(Ab + (size_t)row1 * 1024 + k0 + kc1 * 8);
        uint4 b0 = *(const uint4*)(Bb + (size_t)row0 * 1024 + k0 + kc0 * 8);
        uint4 b1 = *(const uint4*)(Bb + (size_t)row1 * 1024 + k0 + kc1 * 8);
        __syncthreads();   // prev iter's frag reads complete
        *(uint4*)(As + row0 * LDSTRIDE + kc0 * 8) = a0;
        *(uint4*)(As + row1 * LDSTRIDE + kc1 * 8) = a1;
        *(uint4*)(Bs + row0 * LDSTRIDE + kc0 * 8) = b0;
        *(uint4*)(Bs + row1 * LDSTRIDE + kc1 * 8) = b1;
        __syncthreads();
        bf16x8 af[4], bfr[4];
#pragma unroll
        for (int i = 0; i < 4; i++) {
            af[i]  = *(const bf16x8*)(As + (wn0 + i * 16 + l15) * LDSTRIDE + l4 * 8);
            bfr[i] = *(const bf16x8*)(Bs + (wm0 + i * 16 + l15) * LDSTRIDE + l4 * 8);
        }
#pragma unroll
        for (int i = 0; i < 4; i++)
#pragma unroll
            for (int j = 0; j < 4; j++)
                acc[i][j] = __builtin_amdgcn_mfma_f32_16x16x32_bf16(af[i], bfr[j], acc[i][j], 0, 0, 0);
    }

    __bf16* outp = scoresb + ((size_t)b * 256 + nt * 128) * 4096 + (size_t)mt * 128;
#pragma unroll
    for (int i = 0; i < 4; i++)
#pragma unroll
        for (int j = 0; j < 4; j++)
#pragma unroll
            for (int r = 0; r < 4; r++) {
                int n = wn0 + i * 16 + l4 * 4 + r;
                int m = wm0 + j * 16 + l15;
                outp[(size_t)n * 4096 + m] = (__bf16)acc[i][j][r];
            }
}

// ---------------- K3: top-8 (approx, static-index registers) -> exact fp32 rescore -> top-4 ----------------
__global__ __launch_bounds__(256) void topk_rescore_kernel(const __bf16* __restrict__ scoresb,
                                                           const float* __restrict__ teacher,
                                                           const int* __restrict__ ref_perm,
                                                           const float* __restrict__ invnorm,
                                                           int* __restrict__ topk) {
    int row = blockIdx.x;  // b*256+n
    int b = row >> 8, n = row & 255;
    int t = threadIdx.x;
    int lane = t & 63, wave = t >> 6;

    __shared__ float refr[1024];
    __shared__ float cval[32];
    __shared__ int cidx[32];
    __shared__ float exact_v[8];
    __shared__ int exact_i[8];

    const float* Tb = teacher + (size_t)b * 8 * 1024 * 1024;
    int rp = ref_perm[n];
    ((float4*)refr)[t] = ((const float4*)(Tb + (size_t)rp * 1024))[t];

    // stage all 16 score loads up front (latency overlap, no branches between)
    const __bf16* srow = scoresb + (size_t)row * 4096;
    float x[16];
#pragma unroll
    for (int jj = 0; jj < 16; jj++) x[jj] = (float)srow[t + 256 * jj];

    // per-thread sorted top-8 — all register indices compile-time constant
    float v[8]; int ix[8];
#pragma unroll
    for (int i = 0; i < 8; i++) { v[i] = -1e38f; ix[i] = -1; }
#pragma unroll
    for (int jj = 0; jj < 16; jj++) {
        float xv = x[jj]; int xm = t + 256 * jj;
        if (xv > v[7]) {
            v[7] = xv; ix[7] = xm;
#pragma unroll
            for (int i = 7; i > 0; i--)
                if (v[i] > v[i - 1]) {
                    float tv = v[i]; v[i] = v[i - 1]; v[i - 1] = tv;
                    int ti = ix[i]; ix[i] = ix[i - 1]; ix[i - 1] = ti;
                }
        }
    }
    // wave-level top-8: butterfly argmax on heads + static pop (indices unique per m)
    for (int r = 0; r < 8; r++) {
        float bv = v[0]; int bi = ix[0];
        for (int o = 32; o > 0; o >>= 1) {
            float ov = __shfl_xor(bv, o); int oi = __shfl_xor(bi, o);
            if (ov > bv || (ov == bv && oi > bi)) { bv = ov; bi = oi; }
        }
        if (lane == 0) { cval[wave * 8 + r] = bv; cidx[wave * 8 + r] = bi; }
        if (bi == ix[0]) {
            v[0] = v[1]; ix[0] = ix[1];
            v[1] = v[2]; ix[1] = ix[2];
            v[2] = v[3]; ix[2] = ix[3];
            v[3] = v[4]; ix[3] = ix[4];
            v[4] = v[5]; ix[4] = ix[5];
            v[5] = v[6]; ix[5] = ix[6];
            v[6] = v[7]; ix[6] = ix[7];
            v[7] = -1e38f; ix[7] = -1;
        }
    }
    __syncthreads();
    // block merge: wave 0 reduces 32 candidates -> top-8 (scalar regs, static)
    if (wave == 0) {
        float mv = (lane < 32) ? cval[lane] : -1e38f;
        int mi = (lane < 32) ? cidx[lane] : -1;
        for (int r = 0; r < 8; r++) {
            float bv = mv; int bi = mi;
            for (int o = 32; o > 0; o >>= 1) {
                float ov = __shfl_xor(bv, o); int oi = __shfl_xor(bi, o);
                if (ov > bv || (ov == bv && oi > bi)) { bv = ov; bi = oi; }
            }
            if (lane == 0) exact_i[r] = bi;
            if (bi == mi) mv = -1e38f;
        }
    }
    __syncthreads();
    // exact fp32 rescore of the 8 candidates
    for (int c = wave; c < 8; c += 4) {
        int m = exact_i[c];
        int frame = 1 + 2 * (m >> 10), p = m & 1023;
        const float* ext = Tb + ((size_t)frame * 1024 + p) * 1024;
        float s = 0.f;
#pragma unroll
        for (int jj = 0; jj < 16; jj++) {
            int d = lane + 64 * jj;
            s = fmaf(refr[d], ext[d], s);
        }
        for (int o = 32; o > 0; o >>= 1) s += __shfl_xor(s, o);
        if (lane == 0) exact_v[c] = s * invnorm[b * 4096 + m];
    }
    __syncthreads();
    if (t == 0) {
        unsigned used = 0;
        for (int r = 0; r < 4; r++) {
            float bv = -1e38f; int bc = 0;
            for (int c = 0; c < 8; c++)
                if (!(used & (1u << c)) && exact_v[c] > bv) { bv = exact_v[c]; bc = c; }
            used |= 1u << bc;
            topk[row * 4 + r] = exact_i[bc];
        }
    }
}

// ---------------- K4: fused KL branches ----------------
__global__ __launch_bounds__(256) void kl_kernel(const float* __restrict__ teacher,
                                                 const float* __restrict__ student,
                                                 const int* __restrict__ ref_perm,
                                                 const int* __restrict__ shared_perm,
                                                 const int* __restrict__ topk,
                                                 float* __restrict__ acc) {
    int row = blockIdx.x;        // b*256 + n
    int b = row >> 8;
    int n = row & 255;
    int t = threadIdx.x;
    int lane = t & 63, wave = t >> 6;

    __shared__ float rt[1024], rs[1024], st[1024], ss[1024];
    __shared__ float sh[4][1024];
    __shared__ float res3[3];
    if (t < 3) res3[t] = 0.f;

    const float* Tb = teacher + (size_t)b * 8 * 1024 * 1024;
    const float* Sb = student + (size_t)b * 4 * 1024 * 1024;

    int rp = ref_perm[n];
    ((float4*)rt)[t] = ((const float4*)(Tb + (size_t)rp * 1024))[t];
    ((float4*)rs)[t] = ((const float4*)(Sb + (size_t)rp * 1024))[t];
#pragma unroll
    for (int k = 0; k < 4; k++) {
        int idx = topk[row * 4 + k];
        int frame = 1 + 2 * (idx >> 10), p = idx & 1023;
        ((float4*)sh[k])[t] = ((const float4*)(Tb + ((size_t)frame * 1024 + p) * 1024))[t];
    }
    int sp = shared_perm[n];

    for (int ti = 0; ti < 3; ti++) {
        int t_idx = 2 * ti + 2;
        int s_idx = ti + 1;
        __syncthreads();
        ((float4*)st)[t] = ((const float4*)(Tb + ((size_t)t_idx * 1024 + sp) * 1024))[t];
        ((float4*)ss)[t] = ((const float4*)(Sb + ((size_t)s_idx * 1024 + sp) * 1024))[t];
        __syncthreads();

        for (int r = wave; r < 9; r += 4) {
            const float *At, *Bt, *Asx, *Bsx;
            int branch;
            if (r == 0)      { At = rt; Bt = st;        Asx = rs; Bsx = ss;        branch = 0; }
            else if (r < 5)  { At = rt; Bt = sh[r - 1]; Asx = rs; Bsx = sh[r - 1]; branch = 1; }
            else             { At = st; Bt = sh[r - 5]; Asx = ss; Bsx = sh[r - 5]; branch = 2; }

            float dt[16], ds[16];
            float mt = -1e38f, ms = -1e38f;
#pragma unroll
            for (int j = 0; j < 16; j++) {
                int d = lane + 64 * j;
                dt[j] = At[d] - Bt[d];
                ds[j] = Asx[d] - Bsx[d];
                mt = fmaxf(mt, dt[j]);
                ms = fmaxf(ms, ds[j]);
            }
            for (int o = 32; o > 0; o >>= 1) {
                mt = fmaxf(mt, __shfl_xor(mt, o));
                ms = fmaxf(ms, __shfl_xor(ms, o));
            }
            float Zt = 0.f, Zs = 0.f, Tn = 0.f;
#pragma unroll
            for (int j = 0; j < 16; j++) {
                float et = __expf(dt[j] - mt);
                Zt += et;
                Zs += __expf(ds[j] - ms);
                Tn += et * (dt[j] - ds[j]);
            }
            for (int o = 32; o > 0; o >>= 1) {
                Zt += __shfl_xor(Zt, o);
                Zs += __shfl_xor(Zs, o);
                Tn += __shfl_xor(Tn, o);
            }
            if (lane == 0) {
                float kl = Tn / Zt - mt - __logf(Zt) + ms + __logf(Zs);
                float ax = fabsf(kl);
                float h = ax < 0.5f ? ax * ax : ax - 0.25f;
                atomicAdd(&res3[branch], h);
            }
        }
    }
    __syncthreads();
    if (t < 3) atomicAdd(&acc[t], res3[t]);
}

// ---------------- K5: finalize ----------------
__global__ void finalize_kernel(const float* __restrict__ acc, float* __restrict__ out) {
    out[0] = acc[0] / 3072.f + acc[1] / 12288.f + acc[2] / 12288.f;
}

extern "C" void kernel_launch(void* const* d_in, const int* in_sizes, int n_in,
                              void* d_out, int out_size, void* d_ws, size_t ws_size,
                              hipStream_t stream) {
    const float* teacher = (const float*)d_in[0];
    const float* student = (const float*)d_in[1];
    const int* ref_perm = (const int*)d_in[2];
    const int* shared_perm = (const int*)d_in[3];
    float* out = (float*)d_out;

    char* ws = (char*)d_ws;
    float* acc     = (float*)ws;                         // 64 B
    float* invnorm = (float*)(ws + 64);                  // 16384 floats
    int*   topk    = (int*)(ws + 64 + 65536);            // 4096 ints
    __bf16* Abf    = (__bf16*)(ws + 64 + 65536 + 16384); // 4*256*1024
    __bf16* Bbf    = Abf + (size_t)4 * 256 * 1024;       // 4*4096*1024
    __bf16* scoresb = Bbf + (size_t)4 * 4096 * 1024;     // 4*256*4096

    hipMemsetAsync(acc, 0, 64, stream);

    convert_kernel<<<BATCH * 4352, 256, 0, stream>>>(teacher, ref_perm, Abf, Bbf, invnorm);
    mfma_gemm_kernel<<<dim3(32, 2, 4), 256, 0, stream>>>(Abf, Bbf, scoresb);
    topk_rescore_kernel<<<1024, 256, 0, stream>>>(scoresb, teacher, ref_perm, invnorm, topk);
    kl_kernel<<<1024, 256, 0, stream>>>(teacher, student, ref_perm, shared_perm, topk, acc);
    finalize_kernel<<<1, 1, 0, stream>>>(acc, out);
}